// Round 3
// baseline (368.376 us; speedup 1.0000x reference)
//
#include <hip/hip_runtime.h>

#define B_ 4
#define T_ 4096
#define C_ 2048
#define HD_ 128
#define M_ (B_*T_)   // 16384 rows total

typedef __bf16 bf8 __attribute__((ext_vector_type(8)));
typedef unsigned short u16x8 __attribute__((ext_vector_type(8)));
typedef unsigned short u16x4 __attribute__((ext_vector_type(4)));
typedef float f32x4 __attribute__((ext_vector_type(4)));

typedef __attribute__((address_space(3))) unsigned char lds_u8_t;
typedef __attribute__((address_space(1))) const unsigned char gm_u8_t;

// async global->LDS, 16B per lane; LDS dest = wave-uniform base + lane*16
__device__ __forceinline__ void glds16(const void* g, void* l) {
    __builtin_amdgcn_global_load_lds((gm_u8_t*)g, (lds_u8_t*)l, 16, 0, 0);
}

__device__ __forceinline__ unsigned short f2bf(float f) {
    unsigned u = __builtin_bit_cast(unsigned, f);
    u += 0x7FFFu + ((u >> 16) & 1u);   // RNE
    return (unsigned short)(u >> 16);
}
__device__ __forceinline__ float bf2f(unsigned short h) {
    unsigned u = ((unsigned)h) << 16;
    return __builtin_bit_cast(float, u);
}
__device__ __forceinline__ bf8 ld_bf8(const unsigned short* p) {
    u16x8 t = *(const u16x8*)p;
    return __builtin_bit_cast(bf8, t);
}
__device__ __forceinline__ f32x4 zero4() { f32x4 v = {0.f,0.f,0.f,0.f}; return v; }

// ---------------------------------------------------------------------------
// Kernel 0: convert Wq|Wk|Wv (fp32) -> wbf (bf16), contiguous [3][128][2048]
// ---------------------------------------------------------------------------
__global__ __launch_bounds__(256) void wconv(
    const float* __restrict__ Wq, const float* __restrict__ Wk,
    const float* __restrict__ Wv, unsigned short* __restrict__ wbf)
{
    int idx = blockIdx.x * 256 + threadIdx.x;   // 0..98303
    int e = idx * 8;
    int z = e >> 18;                            // 128*2048 = 262144 = 2^18
    int r = e & 262143;
    const float* src = (z == 0 ? Wq : z == 1 ? Wk : Wv) + r;
    float4 a = *(const float4*)src;
    float4 b = *(const float4*)(src + 4);
    u16x8 o;
    o[0]=f2bf(a.x); o[1]=f2bf(a.y); o[2]=f2bf(a.z); o[3]=f2bf(a.w);
    o[4]=f2bf(b.x); o[5]=f2bf(b.y); o[6]=f2bf(b.z); o[7]=f2bf(b.w);
    *(u16x8*)(wbf + e) = o;
}

// ---------------------------------------------------------------------------
// Kernel 1: per-matrix GEMM (x @ Wz^T) + RoPE epilogue.
// grid 768; XCD-aware decode: the 3 z-blocks of one m-tile share id%8 (same
// XCD L2) and are dispatch-adjacent -> x tile read from HBM ~once.
// q is pre-scaled by C^-0.5 * log2(e) so attention softmax runs in exp2 domain.
// ---------------------------------------------------------------------------
__global__ __launch_bounds__(256) void qkv_gemm(
    const float* __restrict__ x, const unsigned short* __restrict__ wbf,
    const float* __restrict__ cosp, const float* __restrict__ sinp,
    unsigned short* __restrict__ qws, unsigned short* __restrict__ kws,
    unsigned short* __restrict__ vws)
{
    __shared__ __align__(16) float xs[64*64];            // 16 KB, [row][64 f32]
    __shared__ __align__(16) unsigned short ws2[128*64]; // 16 KB, [row][64 bf16]

    const int tid = threadIdx.x;
    const int w = tid >> 6, l = tid & 63;
    // XCD-aware decode: xcd = id&7 ; same mt -> same xcd, 3 z consecutive
    const int g = blockIdx.x;
    const int xcd = g & 7;
    const int s = g >> 3;            // 0..95
    const int z = s % 3;
    const int mm = s / 3;            // 0..31
    const int mt = mm * 8 + xcd;
    const int rowbase = mt * 64;

    const int swz = l & 7;
    const int aq  = l >> 4;
    const int coll = l & 15;

    f32x4 acc[2][4];
    #pragma unroll
    for (int i = 0; i < 2; ++i)
        #pragma unroll
        for (int j = 0; j < 4; ++j) acc[i][j] = zero4();

    const unsigned short* wsrc = wbf + (size_t)z * (HD_ * C_);

    for (int kc = 0; kc < C_; kc += 64) {
        __syncthreads();
        // stage x tile: 64 rows x 64 f32 (16 calls, 4/wave), fetch swizzled
        #pragma unroll
        for (int c = 0; c < 4; ++c) {
            int row = w * 16 + c * 4 + aq;
            int fb = coll ^ (row & 7);
            glds16(x + (size_t)(rowbase + row) * C_ + kc + fb * 4,
                   (void*)&xs[(w * 16 + c * 4) * 64]);
        }
        // stage W tile: 128 rows x 64 bf16 (16 calls, 4/wave)
        #pragma unroll
        for (int c = 0; c < 4; ++c) {
            int row = w * 32 + c * 8 + (l >> 3);
            int fb = (l & 7) ^ (row & 7);
            glds16(wsrc + (size_t)row * C_ + kc + fb * 8,
                   (void*)&ws2[(w * 32 + c * 8) * 64]);
        }
        __syncthreads();

        #pragma unroll
        for (int ks_ = 0; ks_ < 2; ++ks_) {
            bf8 a[2];
            #pragma unroll
            for (int mi = 0; mi < 2; ++mi) {
                int row = (w & 1) * 32 + mi * 16 + coll;   // row&7 == swz
                int s0 = ks_ * 8 + aq * 2;
                float4 fa = *(const float4*)&xs[row * 64 + ((s0 ^ swz) << 2)];
                float4 fb = *(const float4*)&xs[row * 64 + (((s0 + 1) ^ swz) << 2)];
                u16x8 t;
                t[0]=f2bf(fa.x); t[1]=f2bf(fa.y); t[2]=f2bf(fa.z); t[3]=f2bf(fa.w);
                t[4]=f2bf(fb.x); t[5]=f2bf(fb.y); t[6]=f2bf(fb.z); t[7]=f2bf(fb.w);
                a[mi] = __builtin_bit_cast(bf8, t);
            }
            #pragma unroll
            for (int nt = 0; nt < 4; ++nt) {
                int row = (w >> 1) * 64 + nt * 16 + coll;  // row&7 == swz
                int slot = (ks_ * 4 + aq) ^ swz;
                bf8 bb = ld_bf8(&ws2[row * 64 + (slot << 3)]);
                acc[0][nt] = __builtin_amdgcn_mfma_f32_16x16x32_bf16(a[0], bb, acc[0][nt], 0, 0, 0);
                acc[1][nt] = __builtin_amdgcn_mfma_f32_16x16x32_bf16(a[1], bb, acc[1][nt], 0, 0, 0);
            }
        }
    }

    // epilogue
    const int rl0 = aq * 4;
    const int cbase = (w >> 1) * 64;
    const int mrow = (w & 1) * 32;
    if (z < 2) {
        // q gets scale*log2e folded in; k unscaled
        const float QSC = 0.022097086912079608f * 1.44269504088896340736f;
        const float fs = (z == 0) ? QSC : 1.0f;
        unsigned short* dst = (z == 0) ? qws : kws;
        #pragma unroll
        for (int mi = 0; mi < 2; ++mi) {
            #pragma unroll
            for (int nt = 0; nt < 4; ++nt) {
                int col = cbase + nt * 16 + coll;
                #pragma unroll
                for (int r = 0; r < 4; ++r) {
                    float val = acc[mi][nt][r];
                    float oth = __shfl_xor(val, 1, 64);
                    int grow = rowbase + mrow + mi * 16 + rl0 + r;
                    int t = grow & (T_ - 1);
                    if ((coll & 1) == 0) {      // even col computes+stores the pair
                        int i = col >> 1;
                        float cv = cosp[t * 64 + i], sv = sinp[t * 64 + i];
                        float o_r = (val * cv - oth * sv) * fs;
                        float o_i = (val * sv + oth * cv) * fs;
                        unsigned pack = (unsigned)f2bf(o_r) | ((unsigned)f2bf(o_i) << 16);
                        *(unsigned*)&dst[(size_t)grow * HD_ + col] = pack;
                    }
                }
            }
        }
    } else {
        const int bq = rowbase >> 12;
        #pragma unroll
        for (int mi = 0; mi < 2; ++mi) {
            int tb = (rowbase + mrow + mi * 16 + rl0) & (T_ - 1);
            #pragma unroll
            for (int nt = 0; nt < 4; ++nt) {
                int col = cbase + nt * 16 + coll;
                u16x4 pk;
                pk[0] = f2bf(acc[mi][nt][0]); pk[1] = f2bf(acc[mi][nt][1]);
                pk[2] = f2bf(acc[mi][nt][2]); pk[3] = f2bf(acc[mi][nt][3]);
                *(u16x4*)&vws[(size_t)(bq * HD_ + col) * T_ + tb] = pk;  // transposed
            }
        }
    }
}

// ---------------------------------------------------------------------------
// Kernel 2: causal flash attention. 64-row Q tiles, 64-col K tiles.
// Grid 256 (heavy-first: qt=63 first). 4 waves; wave w owns q-rows
// [w*16, w*16+16) across ALL 64 K-cols -> wave-local softmax stats, zero
// cross-wave reductions. K/V double-buffered via global_load_lds with
// issue-after-barrier: ONE barrier per iteration, staging of tile t+1
// overlaps compute of tile t. Only the final (diagonal) tile is masked.
// q arrives pre-scaled by C^-0.5*log2e -> softmax in exp2 domain.
// ---------------------------------------------------------------------------
__global__ __launch_bounds__(256) void attn(
    const unsigned short* __restrict__ qws, const unsigned short* __restrict__ kws,
    const unsigned short* __restrict__ vws, float* __restrict__ out)
{
    __shared__ __align__(16) unsigned short qs[64*128];      // 16 KB
    __shared__ __align__(16) unsigned short ks[2][64*128];   // 32 KB
    __shared__ __align__(16) unsigned short vs[2][128*64];   // 32 KB
    __shared__ __align__(16) unsigned short ps[4*16*72];     // 9 KB (per-wave P)

    const int tid = threadIdx.x;
    const int w = tid >> 6, l = tid & 63;
    const int qt = 63 - (blockIdx.x >> 2);   // heavy-first
    const int b  = blockIdx.x & 3;
    const int qbase = qt * 64;
    const size_t rowoff = (size_t)b * T_;

    const int aq = l >> 4, coll = l & 15, swz = l & 7;
    unsigned short* psw = ps + w * (16 * 72);

    // stage Q once (16 calls total, 4/wave)
    #pragma unroll
    for (int c = 0; c < 4; ++c) {
        int row = w * 16 + c * 4 + aq;
        int fb = coll ^ (row & 7);
        glds16(qws + (rowoff + qbase + row) * HD_ + fb * 8,
               (void*)&qs[(w * 16 + c * 4) * 128]);
    }

    auto stageKV = [&](int buf, int st) {
        const int sbase = st * 64;
        #pragma unroll
        for (int c = 0; c < 4; ++c) {                 // K: 64 rows x 128
            int row = w * 16 + c * 4 + aq;
            int fb = coll ^ (row & 7);
            glds16(kws + (rowoff + sbase + row) * HD_ + fb * 8,
                   (void*)&ks[buf][(w * 16 + c * 4) * 128]);
        }
        #pragma unroll
        for (int c = 0; c < 4; ++c) {                 // V: 128 d-rows x 64 s
            int row = w * 32 + c * 8 + (l >> 3);
            int fb = (l & 7) ^ (row & 7);
            glds16(vws + ((size_t)(b * HD_ + row)) * T_ + sbase + fb * 8,
                   (void*)&vs[buf][(w * 32 + c * 8) * 64]);
        }
    };
    stageKV(0, 0);

    float m_r[4] = {-1e30f, -1e30f, -1e30f, -1e30f};
    float l_r[4] = {0.f, 0.f, 0.f, 0.f};
    f32x4 accO[8];
    #pragma unroll
    for (int i = 0; i < 8; ++i) accO[i] = zero4();

    const int nst = qt + 1;

    for (int st = 0; st < nst; ++st) {
        __syncthreads();   // staging of tile st done; prior reads of buf done
        if (st + 1 < nst) stageKV((st + 1) & 1, st + 1);   // async prefetch
        const unsigned short* kcur = ks[st & 1];
        const unsigned short* vcur = vs[st & 1];

        // S = Q K^T (wave: 16 rows x 64 cols)
        f32x4 sacc[4];
        #pragma unroll
        for (int i = 0; i < 4; ++i) sacc[i] = zero4();
        #pragma unroll
        for (int kk = 0; kk < 4; ++kk) {
            const int slot8 = ((kk * 4 + aq) ^ swz) << 3;
            bf8 a = ld_bf8(&qs[(w * 16 + coll) * 128 + slot8]);
            #pragma unroll
            for (int nt = 0; nt < 4; ++nt) {
                bf8 bb = ld_bf8(&kcur[(nt * 16 + coll) * 128 + slot8]);
                sacc[nt] = __builtin_amdgcn_mfma_f32_16x16x32_bf16(a, bb, sacc[nt], 0, 0, 0);
            }
        }

        const bool masked = (st == qt);   // wave-uniform
        #pragma unroll
        for (int r = 0; r < 4; ++r) {
            float s0 = sacc[0][r], s1 = sacc[1][r], s2 = sacc[2][r], s3 = sacc[3][r];
            if (masked) {
                int qi = qbase + w * 16 + aq * 4 + r;
                int ki = qbase + coll;        // sbase == qbase on diagonal tile
                s0 = (ki      > qi) ? -1e30f : s0;
                s1 = (ki + 16 > qi) ? -1e30f : s1;
                s2 = (ki + 32 > qi) ? -1e30f : s2;
                s3 = (ki + 48 > qi) ? -1e30f : s3;
            }
            float mx = fmaxf(fmaxf(s0, s1), fmaxf(s2, s3));
            mx = fmaxf(mx, __shfl_xor(mx, 1, 64));
            mx = fmaxf(mx, __shfl_xor(mx, 2, 64));
            mx = fmaxf(mx, __shfl_xor(mx, 4, 64));
            mx = fmaxf(mx, __shfl_xor(mx, 8, 64));
            float mnew = fmaxf(m_r[r], mx);
            float p0 = __builtin_amdgcn_exp2f(s0 - mnew);
            float p1 = __builtin_amdgcn_exp2f(s1 - mnew);
            float p2 = __builtin_amdgcn_exp2f(s2 - mnew);
            float p3 = __builtin_amdgcn_exp2f(s3 - mnew);
            unsigned short b0 = f2bf(p0), b1 = f2bf(p1), b2 = f2bf(p2), b3 = f2bf(p3);
            const int prow = (aq * 4 + r) * 72;
            psw[prow + coll]      = b0;
            psw[prow + 16 + coll] = b1;
            psw[prow + 32 + coll] = b2;
            psw[prow + 48 + coll] = b3;
            float sum = (bf2f(b0) + bf2f(b1)) + (bf2f(b2) + bf2f(b3));  // bf16-consistent denom
            sum += __shfl_xor(sum, 1, 64);
            sum += __shfl_xor(sum, 2, 64);
            sum += __shfl_xor(sum, 4, 64);
            sum += __shfl_xor(sum, 8, 64);
            float alpha = __builtin_amdgcn_exp2f(m_r[r] - mnew);
            l_r[r] = l_r[r] * alpha + sum;
            m_r[r] = mnew;
            #pragma unroll
            for (int nt = 0; nt < 8; ++nt) accO[nt][r] *= alpha;
        }

        // O += P V (wave: 16 rows x 128 O-cols); ps is wave-private (no barrier)
        #pragma unroll
        for (int kk = 0; kk < 2; ++kk) {
            bf8 a = ld_bf8(&psw[coll * 72 + kk * 32 + aq * 8]);
            const int slot8 = ((kk * 4 + aq) ^ swz) << 3;
            #pragma unroll
            for (int nt = 0; nt < 8; ++nt) {
                bf8 bb = ld_bf8(&vcur[(nt * 16 + coll) * 64 + slot8]);
                accO[nt] = __builtin_amdgcn_mfma_f32_16x16x32_bf16(a, bb, accO[nt], 0, 0, 0);
            }
        }
    }

    // epilogue: out = O / l
    #pragma unroll
    for (int r = 0; r < 4; ++r) {
        float inv = 1.f / l_r[r];
        int grow = qbase + w * 16 + aq * 4 + r;
        #pragma unroll
        for (int nt = 0; nt < 8; ++nt) {
            out[(rowoff + grow) * HD_ + nt * 16 + coll] = accO[nt][r] * inv;
        }
    }
}

extern "C" void kernel_launch(void* const* d_in, const int* in_sizes, int n_in,
                              void* d_out, int out_size, void* d_ws, size_t ws_size,
                              hipStream_t stream) {
    const float* x    = (const float*)d_in[0];
    const float* Wq   = (const float*)d_in[1];
    const float* Wk   = (const float*)d_in[2];
    const float* Wv   = (const float*)d_in[3];
    const float* cosp = (const float*)d_in[4];
    const float* sinp = (const float*)d_in[5];
    float* out = (float*)d_out;

    unsigned short* qws = (unsigned short*)d_ws;          // 16384*128 bf16 (4 MB)
    unsigned short* kws = qws + (size_t)M_ * HD_;         // 4 MB
    unsigned short* vws = kws + (size_t)M_ * HD_;         // (B,128,T) bf16, 4 MB
    unsigned short* wbf = vws + (size_t)M_ * HD_;         // [3][128][2048] bf16, 1.5 MB

    wconv<<<dim3(384), dim3(256), 0, stream>>>(Wq, Wk, Wv, wbf);
    qkv_gemm<<<dim3(768), dim3(256), 0, stream>>>(x, wbf, cosp, sinp, qws, kws, vws);
    attn<<<dim3(B_ * (T_ / 64)), dim3(256), 0, stream>>>(qws, kws, vws, out);
}